// Round 1
// baseline (467.609 us; speedup 1.0000x reference)
//
#include <hip/hip_runtime.h>
#include <stdint.h>

// Problem constants (B=8,T=8192,H=512,E=4,R=16)
#define NTOK 65536
#define HD   512
#define EXP  4
#define RK   16

typedef __attribute__((ext_vector_type(8)))  short short8;
typedef __attribute__((ext_vector_type(4)))  float f32x4;
typedef __attribute__((ext_vector_type(16))) float f32x16;

__device__ __forceinline__ unsigned short f2bf(float f) {
  union { float f; unsigned int u; } c; c.f = f;
  return (unsigned short)((c.u + 0x7fffu + ((c.u >> 16) & 1u)) >> 16);
}

__device__ __forceinline__ void gl_lds16(const void* g, void* l) {
  __builtin_amdgcn_global_load_lds((const __attribute__((address_space(1))) void*)g,
                                   (__attribute__((address_space(3))) void*)l, 16, 0, 0);
}

// ---------------- fused x fp32->bf16 + gating (reads x ONCE) ----------------
__global__ void convgate(const float* __restrict__ x, const float* __restrict__ gw,
                         const float* __restrict__ tw, unsigned short* __restrict__ xbo,
                         float* __restrict__ gates) {
  const int lane = threadIdx.x & 63;
  const int n = blockIdx.x * 4 + (threadIdx.x >> 6);
  const float4* xr = (const float4*)(x + (size_t)n * HD);
  const float4 xa = xr[lane * 2], xb = xr[lane * 2 + 1];
  ushort4 ua, ub;
  ua.x = f2bf(xa.x); ua.y = f2bf(xa.y); ua.z = f2bf(xa.z); ua.w = f2bf(xa.w);
  ub.x = f2bf(xb.x); ub.y = f2bf(xb.y); ub.z = f2bf(xb.z); ub.w = f2bf(xb.w);
  ushort4* xo = (ushort4*)(xbo + (size_t)n * HD);
  xo[lane * 2] = ua; xo[lane * 2 + 1] = ub;
  float s[5];
#pragma unroll
  for (int e = 0; e < 4; e++) {
    const float4* wr = (const float4*)(gw + e * HD);
    const float4 wa = wr[lane * 2], wb = wr[lane * 2 + 1];
    s[e] = xa.x * wa.x + xa.y * wa.y + xa.z * wa.z + xa.w * wa.w
         + xb.x * wb.x + xb.y * wb.y + xb.z * wb.z + xb.w * wb.w;
  }
  {
    const float4* wr = (const float4*)tw;
    const float4 wa = wr[lane * 2], wb = wr[lane * 2 + 1];
    s[4] = xa.x * wa.x + xa.y * wa.y + xa.z * wa.z + xa.w * wa.w
         + xb.x * wb.x + xb.y * wb.y + xb.z * wb.z + xb.w * wb.w;
  }
#pragma unroll
  for (int off = 32; off > 0; off >>= 1)
#pragma unroll
    for (int i = 0; i < 5; i++) s[i] += __shfl_xor(s[i], off, 64);
  float m = fmaxf(fmaxf(s[0], s[1]), fmaxf(s[2], s[3]));
  float e0 = expf(s[0] - m), e1 = expf(s[1] - m), e2 = expf(s[2] - m), e3 = expf(s[3] - m);
  float inv = 1.f / (e0 + e1 + e2 + e3);
  float thr = 0.25f / (1.f + expf(-s[4]));
  float a0 = e0 * inv - thr, a1 = e1 * inv - thr, a2 = e2 * inv - thr, a3 = e3 * inv - thr;
  float w0 = a0 > 0.f ? a0 : 0.f, w1 = a1 > 0.f ? a1 : 0.f;
  float w2 = a2 > 0.f ? a2 : 0.f, w3 = a3 > 0.f ? a3 : 0.f;
  float wsum = w0 + w1 + w2 + w3;
  wsum = (wsum == 0.f) ? 1.f : wsum;
  if (lane < 4) {
    float wv = lane == 0 ? w0 : lane == 1 ? w1 : lane == 2 ? w2 : w3;
    gates[(size_t)n * 4 + lane] = wv / wsum;
  }
}

// ---------------- bulk fp32 -> bf16 (fc1_w) ----------------
__global__ void convk(const float* __restrict__ in, unsigned short* __restrict__ o, int n4) {
  int i = blockIdx.x * 256 + threadIdx.x;
  if (i < n4) {
    float4 v = ((const float4*)in)[i];
    ushort4 u;
    u.x = f2bf(v.x); u.y = f2bf(v.y); u.z = f2bf(v.z); u.w = f2bf(v.w);
    ((ushort4*)o)[i] = u;
  }
}

// ---------------- Mt[d][e*16+r] = sum_o lora_B[e,r,o] * fc2_w[e,d,o] ----------------
__global__ void prep_mt(const float* __restrict__ loraB, const float* __restrict__ fc2,
                        unsigned short* __restrict__ Mt) {
  int idx = blockIdx.x * 256 + threadIdx.x;  // 64*512 = 32768 threads
  int d  = idx & (HD - 1);
  int er = idx >> 9;
  int e = er >> 4, r = er & 15;
  const float4* B = (const float4*)(loraB + ((size_t)e * RK + r) * HD);
  const float4* F = (const float4*)(fc2 + ((size_t)e * HD + d) * HD);
  float a0 = 0.f, a1 = 0.f, a2 = 0.f, a3 = 0.f;
  for (int i = 0; i < HD / 4; i += 4) {
    float4 b0 = B[i],     f0 = F[i];
    float4 b1 = B[i + 1], f1 = F[i + 1];
    float4 b2 = B[i + 2], f2 = F[i + 2];
    float4 b3 = B[i + 3], f3 = F[i + 3];
    a0 += b0.x * f0.x + b0.y * f0.y + b0.z * f0.z + b0.w * f0.w;
    a1 += b1.x * f1.x + b1.y * f1.y + b1.z * f1.z + b1.w * f1.w;
    a2 += b2.x * f2.x + b2.y * f2.y + b2.z * f2.z + b2.w * f2.w;
    a3 += b3.x * f3.x + b3.y * f3.y + b3.z * f3.z + b3.w * f3.w;
  }
  Mt[d * 64 + er] = f2bf(a0 + a1 + a2 + a3);
}

// ---------------- fused fc1 + relu + lora_A -> lw[N][64] (atomic fp32) ----------------
// 256 tok x 256 h tile, BK=32, 8 waves (2M x 4N, per-wave 128x64 => 4x2 frags of 32x32:
// 0.75 ds_read_b128 per MFMA, LDS-read ceiling ~67% MfmaUtil vs 50% at 2x2).
// 4-deep LDS ring (4 x 32KB), staging issued 3 K-tiles ahead via global_load_lds,
// raw s_barrier (NO vmcnt drain), counted s_waitcnt vmcnt(8) at tile boundaries,
// setprio(1) around MFMA clusters (T3+T4+T5).
// LDS layout per tile: A[256 rows][4 granules], B same; slot = row*4 + (g ^ (row&3))
// (full-period XOR => conflict-free ds_read_b128, pre-swizzled global source).
__launch_bounds__(512, 2)
__global__ void fc1_lora(const unsigned short* __restrict__ xb,
                         const unsigned short* __restrict__ w1b,
                         const float* __restrict__ loraA,
                         float* __restrict__ lw) {
  __shared__ __align__(16) char smem[135168];  // ring: 4x32768; epilogue hsm: 256x264x2
  // bid = ntile*8 + eh  ->  XCD = bid%8 = eh: each XCD owns one (e,hq) w-slice (L2-res)
  const int bid = blockIdx.x;           // 2048 blocks
  const int eh = bid & 7;
  const int e = eh >> 1, hq = eh & 1;   // expert, h-half (256 h each)
  const int ntile = bid >> 3;
  const int n0 = ntile * 256;
  const int tid = threadIdx.x;
  const int wave = tid >> 6, lane = tid & 63;
  const int l16 = lane & 15, quad = lane >> 4;
  const int l32 = lane & 31, half = lane >> 5;
  const int wr = wave >> 2, wc = wave & 3;   // 2M x 4N wave grid

  const unsigned short* xg = xb + (size_t)n0 * HD;
  const unsigned short* wg = w1b + ((size_t)e * HD + (size_t)hq * 256) * HD;

  // staging sources: slot S = tid + 512*i; row = S>>2, granule g = (S&3)^(row&3)
  const unsigned short* xsrc[2];
  const unsigned short* wsrc[2];
#pragma unroll
  for (int i = 0; i < 2; i++) {
    const int sl = tid + 512 * i;
    const int row = sl >> 2, g = (sl & 3) ^ (row & 3);
    xsrc[i] = xg + (size_t)row * HD + g * 8;
    wsrc[i] = wg + (size_t)row * HD + g * 8;
  }
  const int wbase = wave * 1024;  // wave-uniform LDS byte base (lane*16 implicit)

  // loop-invariant LDS read byte offsets: [kk][frag]
  int axo[2][4], bxo[2][2];
#pragma unroll
  for (int kk = 0; kk < 2; kk++) {
#pragma unroll
    for (int mb = 0; mb < 4; mb++) {
      const int rowa = wr * 128 + mb * 32 + l32;
      axo[kk][mb] = (rowa * 4 + ((kk * 2 + half) ^ (rowa & 3))) * 16;
    }
#pragma unroll
    for (int nb = 0; nb < 2; nb++) {
      const int rowb = wc * 64 + nb * 32 + l32;
      bxo[kk][nb] = (rowb * 4 + ((kk * 2 + half) ^ (rowb & 3))) * 16;
    }
  }

  f32x16 acc[4][2];
#pragma unroll
  for (int mb = 0; mb < 4; mb++)
#pragma unroll
    for (int nb = 0; nb < 2; nb++)
#pragma unroll
      for (int r = 0; r < 16; r++) acc[mb][nb][r] = 0.f;

  // prologue: stage K-tiles 0,1,2 into ring entries 0,1,2 (4 loads/thread/tile)
#pragma unroll
  for (int tt = 0; tt < 3; tt++) {
    char* As = smem + tt * 32768;
#pragma unroll
    for (int i = 0; i < 2; i++) gl_lds16(xsrc[i] + tt * 32, As + wbase + 8192 * i);
#pragma unroll
    for (int i = 0; i < 2; i++) gl_lds16(wsrc[i] + tt * 32, As + 16384 + wbase + 8192 * i);
  }
  asm volatile("s_waitcnt vmcnt(8)\n\ts_barrier" ::: "memory");  // tile0 resident
  __builtin_amdgcn_sched_barrier(0);

  // main loop: 16 K-tiles of 32; 2 phases/tile; never vmcnt(0) until the tail
#pragma unroll
  for (int t = 0; t < 16; t++) {
    char* Ab = smem + (t & 3) * 32768;
    char* Bb = Ab + 16384;
    char* As = smem + ((t + 3) & 3) * 32768;  // freed at the (t-1)->t boundary
    const int kos = (t + 3) * 32;
#pragma unroll
    for (int p = 0; p < 2; p++) {
      short8 af[4], bf[2];
#pragma unroll
      for (int mb = 0; mb < 4; mb++) af[mb] = *(const short8*)(Ab + axo[p][mb]);
#pragma unroll
      for (int nb = 0; nb < 2; nb++) bf[nb] = *(const short8*)(Bb + bxo[p][nb]);
      if (t < 13) {  // issue tile t+3 (2 loads/phase)
        gl_lds16(xsrc[p] + kos, As + wbase + 8192 * p);
        gl_lds16(wsrc[p] + kos, As + 16384 + wbase + 8192 * p);
      }
      asm volatile("s_barrier" ::: "memory");
      __builtin_amdgcn_s_setprio(1);
#pragma unroll
      for (int mb = 0; mb < 4; mb++)
#pragma unroll
        for (int nb = 0; nb < 2; nb++)
          acc[mb][nb] = __builtin_amdgcn_mfma_f32_32x32x16_bf16(af[mb], bf[nb], acc[mb][nb], 0, 0, 0);
      __builtin_amdgcn_s_setprio(0);
    }
    // boundary: tile t+1 must be resident; newest-8 outstanding = tiles t+2,t+3
    if (t < 13) {
      asm volatile("s_waitcnt lgkmcnt(0)\n\ts_waitcnt vmcnt(8)\n\ts_barrier" ::: "memory");
    } else if (t == 13) {
      asm volatile("s_waitcnt lgkmcnt(0)\n\ts_waitcnt vmcnt(4)\n\ts_barrier" ::: "memory");
    } else if (t == 14) {
      asm volatile("s_waitcnt lgkmcnt(0)\n\ts_waitcnt vmcnt(0)\n\ts_barrier" ::: "memory");
    } else {
      asm volatile("s_waitcnt lgkmcnt(0)\n\ts_barrier" ::: "memory");
    }
    __builtin_amdgcn_sched_barrier(0);
  }

  // stage 2: relu -> bf16 hidden to block-shared LDS [256 tok][264 shorts]
  unsigned short* hsm = (unsigned short*)smem;
#pragma unroll
  for (int mb = 0; mb < 4; mb++)
#pragma unroll
    for (int nb = 0; nb < 2; nb++) {
      const int colh = wc * 64 + nb * 32 + l32;
#pragma unroll
      for (int r = 0; r < 16; r++) {
        const int tok = wr * 128 + mb * 32 + 4 * half + (r & 3) + 8 * (r >> 2);
        float v = acc[mb][nb][r];
        v = v > 0.f ? v : 0.f;
        hsm[tok * 264 + colh] = f2bf(v);
      }
    }
  __syncthreads();

  // lo[tok][r] over this block's 256 h; wave handles tokens wave*32..+31
  const float* Ae = loraA + (size_t)e * HD * RK;
  const int hA0 = hq * 256;
  f32x4 lo[2];
#pragma unroll
  for (int mf = 0; mf < 2; mf++)
#pragma unroll
    for (int i = 0; i < 4; i++) lo[mf][i] = 0.f;
#pragma unroll
  for (int k2 = 0; k2 < 8; k2++) {
    short8 a2[2];
#pragma unroll
    for (int mf = 0; mf < 2; mf++) {
      const int tok = wave * 32 + mf * 16 + l16;
      a2[mf] = *(const short8*)(hsm + tok * 264 + k2 * 32 + quad * 8);
    }
    union { short8 v; unsigned short sv[8]; } b2;
#pragma unroll
    for (int j = 0; j < 8; j++)
      b2.sv[j] = f2bf(Ae[(size_t)(hA0 + k2 * 32 + quad * 8 + j) * RK + l16]);
#pragma unroll
    for (int mf = 0; mf < 2; mf++)
      lo[mf] = __builtin_amdgcn_mfma_f32_16x16x32_bf16(a2[mf], b2.v, lo[mf], 0, 0, 0);
  }
#pragma unroll
  for (int mf = 0; mf < 2; mf++)
#pragma unroll
    for (int i = 0; i < 4; i++)
      atomicAdd(lw + (size_t)(n0 + wave * 32 + mf * 16 + quad * 4 + i) * 64 + e * 16 + l16, lo[mf][i]);
}

// ---------------- combine: out[n][d] = sum_k (lw[n][k]*gate[n][k/16]) * Mt[d][k] ----------------
// Mt staged into LDS with full-period XOR-swizzled 16B granules (conflict-free).
__launch_bounds__(256, 2)
__global__ void combine_k(const float* __restrict__ lw, const float* __restrict__ gates,
                          const unsigned short* __restrict__ Mt, float* __restrict__ out) {
  __shared__ __align__(16) char smem[65536];
  const int n0 = blockIdx.x * 64;
  const int tid = threadIdx.x;
  const int wave = tid >> 6, lane = tid & 63, quad = lane >> 4, l16 = lane & 15;
#pragma unroll
  for (int i = 0; i < 16; i++) {
    const int slot = tid + 256 * i;          // 0..4095
    const int row = slot >> 3;
    const int g = (slot & 7) ^ (row & 7);
    *(uint4*)(smem + slot * 16) = *(const uint4*)(Mt + row * 64 + g * 8);
  }
  __syncthreads();
  f32x4 acc[4][8];
#pragma unroll
  for (int a = 0; a < 4; a++)
#pragma unroll
    for (int b = 0; b < 8; b++)
#pragma unroll
      for (int i = 0; i < 4; i++) acc[a][b][i] = 0.f;
#pragma unroll
  for (int ks = 0; ks < 2; ks++) {
    short8 af[4], bfr[8];
#pragma unroll
    for (int mf = 0; mf < 4; mf++) {
      const int n = n0 + mf * 16 + l16;
      const float* lr = lw + (size_t)n * 64 + ks * 32 + quad * 8;
      float4 u0 = *(const float4*)lr;
      float4 u1 = *(const float4*)(lr + 4);
      const float g = gates[(size_t)n * 4 + ((ks * 32 + quad * 8) >> 4)];
      union { short8 v; unsigned short s[8]; } a;
      a.s[0] = f2bf(u0.x * g); a.s[1] = f2bf(u0.y * g);
      a.s[2] = f2bf(u0.z * g); a.s[3] = f2bf(u0.w * g);
      a.s[4] = f2bf(u1.x * g); a.s[5] = f2bf(u1.y * g);
      a.s[6] = f2bf(u1.z * g); a.s[7] = f2bf(u1.w * g);
      af[mf] = a.v;
    }
#pragma unroll
    for (int nf = 0; nf < 8; nf++) {
      const int row = wave * 128 + nf * 16 + l16;
      const int slot = row * 8 + ((ks * 4 + quad) ^ (row & 7));
      bfr[nf] = *(const short8*)(smem + slot * 16);
    }
#pragma unroll
    for (int mf = 0; mf < 4; mf++)
#pragma unroll
      for (int nf = 0; nf < 8; nf++)
        acc[mf][nf] = __builtin_amdgcn_mfma_f32_16x16x32_bf16(af[mf], bfr[nf], acc[mf][nf], 0, 0, 0);
  }
#pragma unroll
  for (int mf = 0; mf < 4; mf++)
#pragma unroll
    for (int nf = 0; nf < 8; nf++) {
      const int d = wave * 128 + nf * 16 + l16;
#pragma unroll
      for (int i = 0; i < 4; i++)
        out[(size_t)(n0 + mf * 16 + quad * 4 + i) * HD + d] = acc[mf][nf][i];
    }
}

// ---------------- launch ----------------
extern "C" void kernel_launch(void* const* d_in, const int* in_sizes, int n_in,
                              void* d_out, int out_size, void* d_ws, size_t ws_size,
                              hipStream_t stream) {
  const float* x      = (const float*)d_in[0];
  const float* gate_w = (const float*)d_in[1];
  const float* thr_w  = (const float*)d_in[2];
  const float* fc1_w  = (const float*)d_in[3];
  const float* lora_A = (const float*)d_in[4];
  const float* lora_B = (const float*)d_in[5];
  const float* fc2_w  = (const float*)d_in[6];
  float* out = (float*)d_out;
  char* ws = (char*)d_ws;

  unsigned short* xbp = (unsigned short*)(ws);                   // 67108864 B
  unsigned short* w1b = (unsigned short*)(ws + 67108864);        //  2097152 B
  unsigned short* Mt  = (unsigned short*)(ws + 69206016);        //    65536 B
  float*          gts = (float*)(ws + 69271552);                 //  1048576 B
  float*          lwp = (float*)(ws + 70320128);                 // 16777216 B

  hipMemsetAsync(lwp, 0, (size_t)NTOK * 64 * sizeof(float), stream);
  convgate<<<NTOK / 4, 256, 0, stream>>>(x, gate_w, thr_w, xbp, gts);
  convk<<<1024, 256, 0, stream>>>(fc1_w, w1b, EXP * HD * HD / 4);
  prep_mt<<<128, 256, 0, stream>>>(lora_B, fc2_w, Mt);
  fc1_lora<<<2048, 512, 0, stream>>>(xbp, w1b, lora_A, lwp);
  combine_k<<<NTOK / 64, 256, 0, stream>>>(lwp, gts, Mt, out);
}

// Round 2
// 440.739 us; speedup vs baseline: 1.0610x; 1.0610x over previous
//
#include <hip/hip_runtime.h>
#include <stdint.h>

// Problem constants (B=8,T=8192,H=512,E=4,R=16)
#define NTOK 65536
#define HD   512
#define EXP  4
#define RK   16

typedef __attribute__((ext_vector_type(8)))  short short8;
typedef __attribute__((ext_vector_type(4)))  float f32x4;
typedef __attribute__((ext_vector_type(16))) float f32x16;

__device__ __forceinline__ unsigned short f2bf(float f) {
  union { float f; unsigned int u; } c; c.f = f;
  return (unsigned short)((c.u + 0x7fffu + ((c.u >> 16) & 1u)) >> 16);
}

__device__ __forceinline__ void gl_lds16(const void* g, void* l) {
  __builtin_amdgcn_global_load_lds((const __attribute__((address_space(1))) void*)g,
                                   (__attribute__((address_space(3))) void*)l, 16, 0, 0);
}

// ---------------- fused x fp32->bf16 + gating (reads x ONCE) ----------------
__global__ void convgate(const float* __restrict__ x, const float* __restrict__ gw,
                         const float* __restrict__ tw, unsigned short* __restrict__ xbo,
                         float* __restrict__ gates) {
  const int lane = threadIdx.x & 63;
  const int n = blockIdx.x * 4 + (threadIdx.x >> 6);
  const float4* xr = (const float4*)(x + (size_t)n * HD);
  const float4 xa = xr[lane * 2], xb = xr[lane * 2 + 1];
  ushort4 ua, ub;
  ua.x = f2bf(xa.x); ua.y = f2bf(xa.y); ua.z = f2bf(xa.z); ua.w = f2bf(xa.w);
  ub.x = f2bf(xb.x); ub.y = f2bf(xb.y); ub.z = f2bf(xb.z); ub.w = f2bf(xb.w);
  ushort4* xo = (ushort4*)(xbo + (size_t)n * HD);
  xo[lane * 2] = ua; xo[lane * 2 + 1] = ub;
  float s[5];
#pragma unroll
  for (int e = 0; e < 4; e++) {
    const float4* wr = (const float4*)(gw + e * HD);
    const float4 wa = wr[lane * 2], wb = wr[lane * 2 + 1];
    s[e] = xa.x * wa.x + xa.y * wa.y + xa.z * wa.z + xa.w * wa.w
         + xb.x * wb.x + xb.y * wb.y + xb.z * wb.z + xb.w * wb.w;
  }
  {
    const float4* wr = (const float4*)tw;
    const float4 wa = wr[lane * 2], wb = wr[lane * 2 + 1];
    s[4] = xa.x * wa.x + xa.y * wa.y + xa.z * wa.z + xa.w * wa.w
         + xb.x * wb.x + xb.y * wb.y + xb.z * wb.z + xb.w * wb.w;
  }
#pragma unroll
  for (int off = 32; off > 0; off >>= 1)
#pragma unroll
    for (int i = 0; i < 5; i++) s[i] += __shfl_xor(s[i], off, 64);
  float m = fmaxf(fmaxf(s[0], s[1]), fmaxf(s[2], s[3]));
  float e0 = expf(s[0] - m), e1 = expf(s[1] - m), e2 = expf(s[2] - m), e3 = expf(s[3] - m);
  float inv = 1.f / (e0 + e1 + e2 + e3);
  float thr = 0.25f / (1.f + expf(-s[4]));
  float a0 = e0 * inv - thr, a1 = e1 * inv - thr, a2 = e2 * inv - thr, a3 = e3 * inv - thr;
  float w0 = a0 > 0.f ? a0 : 0.f, w1 = a1 > 0.f ? a1 : 0.f;
  float w2 = a2 > 0.f ? a2 : 0.f, w3 = a3 > 0.f ? a3 : 0.f;
  float wsum = w0 + w1 + w2 + w3;
  wsum = (wsum == 0.f) ? 1.f : wsum;
  if (lane < 4) {
    float wv = lane == 0 ? w0 : lane == 1 ? w1 : lane == 2 ? w2 : w3;
    gates[(size_t)n * 4 + lane] = wv / wsum;
  }
}

// ---------------- bulk fp32 -> bf16 (fc1_w) ----------------
__global__ void convk(const float* __restrict__ in, unsigned short* __restrict__ o, int n4) {
  int i = blockIdx.x * 256 + threadIdx.x;
  if (i < n4) {
    float4 v = ((const float4*)in)[i];
    ushort4 u;
    u.x = f2bf(v.x); u.y = f2bf(v.y); u.z = f2bf(v.z); u.w = f2bf(v.w);
    ((ushort4*)o)[i] = u;
  }
}

// ---------------- Mt[d][e*16+r] = sum_o lora_B[e,r,o] * fc2_w[e,d,o] ----------------
__global__ void prep_mt(const float* __restrict__ loraB, const float* __restrict__ fc2,
                        unsigned short* __restrict__ Mt) {
  int idx = blockIdx.x * 256 + threadIdx.x;  // 64*512 = 32768 threads
  int d  = idx & (HD - 1);
  int er = idx >> 9;
  int e = er >> 4, r = er & 15;
  const float4* B = (const float4*)(loraB + ((size_t)e * RK + r) * HD);
  const float4* F = (const float4*)(fc2 + ((size_t)e * HD + d) * HD);
  float a0 = 0.f, a1 = 0.f, a2 = 0.f, a3 = 0.f;
  for (int i = 0; i < HD / 4; i += 4) {
    float4 b0 = B[i],     f0 = F[i];
    float4 b1 = B[i + 1], f1 = F[i + 1];
    float4 b2 = B[i + 2], f2 = F[i + 2];
    float4 b3 = B[i + 3], f3 = F[i + 3];
    a0 += b0.x * f0.x + b0.y * f0.y + b0.z * f0.z + b0.w * f0.w;
    a1 += b1.x * f1.x + b1.y * f1.y + b1.z * f1.z + b1.w * f1.w;
    a2 += b2.x * f2.x + b2.y * f2.y + b2.z * f2.z + b2.w * f2.w;
    a3 += b3.x * f3.x + b3.y * f3.y + b3.z * f3.z + b3.w * f3.w;
  }
  Mt[d * 64 + er] = f2bf(a0 + a1 + a2 + a3);
}

// ---------------- fused fc1 + relu + lora_A -> lw[N][64] (atomic fp32) ----------------
// 256 tok x 256 h tile, BK=32, 8 waves (2M x 4N, per-wave 128x64 => 4x2 frags of 32x32:
// 0.75 ds_read_b128 per MFMA). Ring-4 LDS (4 x 32KB), staging 3 K-tiles ahead via
// global_load_lds, raw s_barrier, counted s_waitcnt vmcnt(8), setprio around MFMA.
//
// LDS layout (fix for round-1's 8-way conflict): BK=32 rows are 64 B, so pack TWO
// token rows per 128-B super-row: slot = sr*8 + (g8 ^ (sr&7)), g8 = (row&1)*4 + g.
// Every consecutive-8-lane phase of a wave64 ds_read_b128 then tiles all 32 banks
// exactly once (same invariant as the proven BK=64 period-8 layout). Staging keeps
// linear LDS dest (global_load_lds) with pre-swizzled per-lane global source.
//
// XCD decode (fix for round-1's 4x x-refetch): XCD = bid%8, so put eh in the
// WITHIN-XCD index: c=bid&7 owns ntiles c*32..c*32+31, eh fastest -> the 8 (e,hq)
// blocks of one token tile run back-to-back on ONE XCD; x-tile hits L2 7/8 times.
__launch_bounds__(512, 2)
__global__ void fc1_lora(const unsigned short* __restrict__ xb,
                         const unsigned short* __restrict__ w1b,
                         const float* __restrict__ loraA,
                         float* __restrict__ lw) {
  __shared__ __align__(16) char smem[135168];  // ring: 4x32768; epilogue hsm: 256x264x2
  const int bid = blockIdx.x;           // 2048 blocks
  const int c = bid & 7;                // XCD
  const int j = bid >> 3;               // 0..255 within XCD
  const int eh = j & 7;
  const int e = eh >> 1, hq = eh & 1;   // expert, h-half (256 h each)
  const int ntile = c * 32 + (j >> 3);
  const int n0 = ntile * 256;
  const int tid = threadIdx.x;
  const int wave = tid >> 6, lane = tid & 63;
  const int l16 = lane & 15, quad = lane >> 4;
  const int l32 = lane & 31, half = lane >> 5;
  const int wr = wave >> 2, wc = wave & 3;   // 2M x 4N wave grid

  const unsigned short* xg = xb + (size_t)n0 * HD;
  const unsigned short* wg = w1b + ((size_t)e * HD + (size_t)hq * 256) * HD;

  // staging sources: slot S = tid + 512*i; sr = S>>3, g8 = (S&7)^(sr&7),
  // row = sr*2 + (g8>>2), granule = g8&3
  const unsigned short* xsrc[2];
  const unsigned short* wsrc[2];
#pragma unroll
  for (int i = 0; i < 2; i++) {
    const int sl = tid + 512 * i;
    const int sr = sl >> 3, g8 = (sl & 7) ^ (sr & 7);
    const int row = sr * 2 + (g8 >> 2), g = g8 & 3;
    xsrc[i] = xg + (size_t)row * HD + g * 8;
    wsrc[i] = wg + (size_t)row * HD + g * 8;
  }
  const int wbase = wave * 1024;  // wave-uniform LDS byte base (lane*16 implicit)

  // loop-invariant LDS read byte offsets: [kk][frag]; needed granule = kk*2+half
  int axo[2][4], bxo[2][2];
#pragma unroll
  for (int kk = 0; kk < 2; kk++) {
#pragma unroll
    for (int mb = 0; mb < 4; mb++) {
      const int rowa = wr * 128 + mb * 32 + l32;
      const int sr = rowa >> 1, g8 = (rowa & 1) * 4 + kk * 2 + half;
      axo[kk][mb] = (sr * 8 + (g8 ^ (sr & 7))) * 16;
    }
#pragma unroll
    for (int nb = 0; nb < 2; nb++) {
      const int rowb = wc * 64 + nb * 32 + l32;
      const int sr = rowb >> 1, g8 = (rowb & 1) * 4 + kk * 2 + half;
      bxo[kk][nb] = (sr * 8 + (g8 ^ (sr & 7))) * 16;
    }
  }

  f32x16 acc[4][2];
#pragma unroll
  for (int mb = 0; mb < 4; mb++)
#pragma unroll
    for (int nb = 0; nb < 2; nb++)
#pragma unroll
      for (int r = 0; r < 16; r++) acc[mb][nb][r] = 0.f;

  // prologue: stage K-tiles 0,1,2 into ring entries 0,1,2 (4 loads/thread/tile)
#pragma unroll
  for (int tt = 0; tt < 3; tt++) {
    char* As = smem + tt * 32768;
#pragma unroll
    for (int i = 0; i < 2; i++) gl_lds16(xsrc[i] + tt * 32, As + wbase + 8192 * i);
#pragma unroll
    for (int i = 0; i < 2; i++) gl_lds16(wsrc[i] + tt * 32, As + 16384 + wbase + 8192 * i);
  }
  asm volatile("s_waitcnt vmcnt(8)\n\ts_barrier" ::: "memory");  // tile0 resident
  __builtin_amdgcn_sched_barrier(0);

  // main loop: 16 K-tiles of 32; 2 phases/tile; never vmcnt(0) until the tail
#pragma unroll
  for (int t = 0; t < 16; t++) {
    char* Ab = smem + (t & 3) * 32768;
    char* Bb = Ab + 16384;
    char* As = smem + ((t + 3) & 3) * 32768;  // freed at the (t-1)->t boundary
    const int kos = (t + 3) * 32;
#pragma unroll
    for (int p = 0; p < 2; p++) {
      short8 af[4], bf[2];
#pragma unroll
      for (int mb = 0; mb < 4; mb++) af[mb] = *(const short8*)(Ab + axo[p][mb]);
#pragma unroll
      for (int nb = 0; nb < 2; nb++) bf[nb] = *(const short8*)(Bb + bxo[p][nb]);
      if (t < 13) {  // issue tile t+3 (2 loads/phase)
        gl_lds16(xsrc[p] + kos, As + wbase + 8192 * p);
        gl_lds16(wsrc[p] + kos, As + 16384 + wbase + 8192 * p);
      }
      asm volatile("s_barrier" ::: "memory");
      __builtin_amdgcn_s_setprio(1);
#pragma unroll
      for (int mb = 0; mb < 4; mb++)
#pragma unroll
        for (int nb = 0; nb < 2; nb++)
          acc[mb][nb] = __builtin_amdgcn_mfma_f32_32x32x16_bf16(af[mb], bf[nb], acc[mb][nb], 0, 0, 0);
      __builtin_amdgcn_s_setprio(0);
    }
    // boundary: tile t+1 must be resident; newest-8 outstanding = tiles t+2,t+3
    if (t < 13) {
      asm volatile("s_waitcnt lgkmcnt(0)\n\ts_waitcnt vmcnt(8)\n\ts_barrier" ::: "memory");
    } else if (t == 13) {
      asm volatile("s_waitcnt lgkmcnt(0)\n\ts_waitcnt vmcnt(4)\n\ts_barrier" ::: "memory");
    } else if (t == 14) {
      asm volatile("s_waitcnt lgkmcnt(0)\n\ts_waitcnt vmcnt(0)\n\ts_barrier" ::: "memory");
    } else {
      asm volatile("s_waitcnt lgkmcnt(0)\n\ts_barrier" ::: "memory");
    }
    __builtin_amdgcn_sched_barrier(0);
  }

  // stage 2: relu -> bf16 hidden to block-shared LDS [256 tok][264 shorts]
  unsigned short* hsm = (unsigned short*)smem;
#pragma unroll
  for (int mb = 0; mb < 4; mb++)
#pragma unroll
    for (int nb = 0; nb < 2; nb++) {
      const int colh = wc * 64 + nb * 32 + l32;
#pragma unroll
      for (int r = 0; r < 16; r++) {
        const int tok = wr * 128 + mb * 32 + 4 * half + (r & 3) + 8 * (r >> 2);
        float v = acc[mb][nb][r];
        v = v > 0.f ? v : 0.f;
        hsm[tok * 264 + colh] = f2bf(v);
      }
    }
  __syncthreads();

  // lo[tok][r] over this block's 256 h; wave handles tokens wave*32..+31
  const float* Ae = loraA + (size_t)e * HD * RK;
  const int hA0 = hq * 256;
  f32x4 lo[2];
#pragma unroll
  for (int mf = 0; mf < 2; mf++)
#pragma unroll
    for (int i = 0; i < 4; i++) lo[mf][i] = 0.f;
#pragma unroll
  for (int k2 = 0; k2 < 8; k2++) {
    short8 a2[2];
#pragma unroll
    for (int mf = 0; mf < 2; mf++) {
      const int tok = wave * 32 + mf * 16 + l16;
      a2[mf] = *(const short8*)(hsm + tok * 264 + k2 * 32 + quad * 8);
    }
    union { short8 v; unsigned short sv[8]; } b2;
#pragma unroll
    for (int j2 = 0; j2 < 8; j2++)
      b2.sv[j2] = f2bf(Ae[(size_t)(hA0 + k2 * 32 + quad * 8 + j2) * RK + l16]);
#pragma unroll
    for (int mf = 0; mf < 2; mf++)
      lo[mf] = __builtin_amdgcn_mfma_f32_16x16x32_bf16(a2[mf], b2.v, lo[mf], 0, 0, 0);
  }
#pragma unroll
  for (int mf = 0; mf < 2; mf++)
#pragma unroll
    for (int i = 0; i < 4; i++)
      atomicAdd(lw + (size_t)(n0 + wave * 32 + mf * 16 + quad * 4 + i) * 64 + e * 16 + l16, lo[mf][i]);
}

// ---------------- combine: out[n][d] = sum_k (lw[n][k]*gate[n][k/16]) * Mt[d][k] ----------------
// Mt staged into LDS with full-period XOR-swizzled 16B granules (conflict-free).
__launch_bounds__(256, 2)
__global__ void combine_k(const float* __restrict__ lw, const float* __restrict__ gates,
                          const unsigned short* __restrict__ Mt, float* __restrict__ out) {
  __shared__ __align__(16) char smem[65536];
  const int n0 = blockIdx.x * 64;
  const int tid = threadIdx.x;
  const int wave = tid >> 6, lane = tid & 63, quad = lane >> 4, l16 = lane & 15;
#pragma unroll
  for (int i = 0; i < 16; i++) {
    const int slot = tid + 256 * i;          // 0..4095
    const int row = slot >> 3;
    const int g = (slot & 7) ^ (row & 7);
    *(uint4*)(smem + slot * 16) = *(const uint4*)(Mt + row * 64 + g * 8);
  }
  __syncthreads();
  f32x4 acc[4][8];
#pragma unroll
  for (int a = 0; a < 4; a++)
#pragma unroll
    for (int b = 0; b < 8; b++)
#pragma unroll
      for (int i = 0; i < 4; i++) acc[a][b][i] = 0.f;
#pragma unroll
  for (int ks = 0; ks < 2; ks++) {
    short8 af[4], bfr[8];
#pragma unroll
    for (int mf = 0; mf < 4; mf++) {
      const int n = n0 + mf * 16 + l16;
      const float* lr = lw + (size_t)n * 64 + ks * 32 + quad * 8;
      float4 u0 = *(const float4*)lr;
      float4 u1 = *(const float4*)(lr + 4);
      const float g = gates[(size_t)n * 4 + ((ks * 32 + quad * 8) >> 4)];
      union { short8 v; unsigned short s[8]; } a;
      a.s[0] = f2bf(u0.x * g); a.s[1] = f2bf(u0.y * g);
      a.s[2] = f2bf(u0.z * g); a.s[3] = f2bf(u0.w * g);
      a.s[4] = f2bf(u1.x * g); a.s[5] = f2bf(u1.y * g);
      a.s[6] = f2bf(u1.z * g); a.s[7] = f2bf(u1.w * g);
      af[mf] = a.v;
    }
#pragma unroll
    for (int nf = 0; nf < 8; nf++) {
      const int row = wave * 128 + nf * 16 + l16;
      const int slot = row * 8 + ((ks * 4 + quad) ^ (row & 7));
      bfr[nf] = *(const short8*)(smem + slot * 16);
    }
#pragma unroll
    for (int mf = 0; mf < 4; mf++)
#pragma unroll
      for (int nf = 0; nf < 8; nf++)
        acc[mf][nf] = __builtin_amdgcn_mfma_f32_16x16x32_bf16(af[mf], bfr[nf], acc[mf][nf], 0, 0, 0);
  }
#pragma unroll
  for (int mf = 0; mf < 4; mf++)
#pragma unroll
    for (int nf = 0; nf < 8; nf++) {
      const int d = wave * 128 + nf * 16 + l16;
#pragma unroll
      for (int i = 0; i < 4; i++)
        out[(size_t)(n0 + mf * 16 + quad * 4 + i) * HD + d] = acc[mf][nf][i];
    }
}

// ---------------- launch ----------------
extern "C" void kernel_launch(void* const* d_in, const int* in_sizes, int n_in,
                              void* d_out, int out_size, void* d_ws, size_t ws_size,
                              hipStream_t stream) {
  const float* x      = (const float*)d_in[0];
  const float* gate_w = (const float*)d_in[1];
  const float* thr_w  = (const float*)d_in[2];
  const float* fc1_w  = (const float*)d_in[3];
  const float* lora_A = (const float*)d_in[4];
  const float* lora_B = (const float*)d_in[5];
  const float* fc2_w  = (const float*)d_in[6];
  float* out = (float*)d_out;
  char* ws = (char*)d_ws;

  unsigned short* xbp = (unsigned short*)(ws);                   // 67108864 B
  unsigned short* w1b = (unsigned short*)(ws + 67108864);        //  2097152 B
  unsigned short* Mt  = (unsigned short*)(ws + 69206016);        //    65536 B
  float*          gts = (float*)(ws + 69271552);                 //  1048576 B
  float*          lwp = (float*)(ws + 70320128);                 // 16777216 B

  hipMemsetAsync(lwp, 0, (size_t)NTOK * 64 * sizeof(float), stream);
  convgate<<<NTOK / 4, 256, 0, stream>>>(x, gate_w, thr_w, xbp, gts);
  convk<<<1024, 256, 0, stream>>>(fc1_w, w1b, EXP * HD * HD / 4);
  prep_mt<<<128, 256, 0, stream>>>(lora_B, fc2_w, Mt);
  fc1_lora<<<2048, 512, 0, stream>>>(xbp, w1b, lora_A, lwp);
  combine_k<<<NTOK / 64, 256, 0, stream>>>(lwp, gts, Mt, out);
}